// Round 9
// baseline (71.220 us; speedup 1.0000x reference)
//
#include <hip/hip_runtime.h>

// out[i] = P(x[i]) / (|x[i]*Q(x[i])| + 1)
//
// R8 diagnosis: all forms plateau at true ~11.7us because the compiler keeps
// coefficient s_loads IN the Horner loop (SGPR pressure), batched with
// s_waitcnt lgkmcnt right before use -> all 8 lockstep waves/SIMD stall
// together -> VALUBusy 63% (R5 probe). R4 (2x s_load batches) was worst,
// confirming.
//
// Fix: force coefficients into VGPRs structurally. Stage 128 coeffs in LDS
// (once per block), copy to per-thread local arrays via ds_read_b128 (LDS
// reads always land in VGPRs; cannot be turned back into in-loop s_loads).
// Two passes (num: cn[64], den: cd[64]) keep peak live ~100 VGPR under the
// launch_bounds(256,4) cap of 128 -> 4 waves/SIMD. Horner body has ZERO
// memory ops: pure v_fma_f32 stream, 2016 issue-cyc/wave.
// Floor: 6.7us issue + prologue -> predict true ~7.5-8us.

#define EPT 8

__global__ __launch_bounds__(256, 4) void rationals_kernel(
    const float* __restrict__ x,
    const float* __restrict__ coeff,
    float* __restrict__ out, int N) {
    __shared__ float sc[128];
    if (threadIdx.x < 128) sc[threadIdx.x] = coeff[threadIdx.x];
    __syncthreads();

    // grid sized exactly: N == gridDim.x * blockDim.x * EPT
    const int idx = (blockIdx.x * blockDim.x + threadIdx.x) * EPT;

    float4 xa = *reinterpret_cast<const float4*>(x + idx);
    float4 xb = *reinterpret_cast<const float4*>(x + idx + 4);
    float xs[EPT] = {xa.x, xa.y, xa.z, xa.w, xb.x, xb.y, xb.z, xb.w};

    // ---- pass 1: numerator, coeffs sc[0..63] -> VGPR array ----
    float num[EPT];
    {
        float cn[64];
#pragma unroll
        for (int q = 0; q < 16; ++q) {
            float4 v = *reinterpret_cast<const float4*>(&sc[4 * q]);
            cn[4 * q] = v.x; cn[4 * q + 1] = v.y;
            cn[4 * q + 2] = v.z; cn[4 * q + 3] = v.w;
        }
        float h[EPT];
#pragma unroll
        for (int j = 0; j < EPT; ++j) h[j] = cn[63];
#pragma unroll
        for (int p = 62; p >= 0; --p)
#pragma unroll
            for (int j = 0; j < EPT; ++j)
                h[j] = fmaf(h[j], xs[j], cn[p]);
#pragma unroll
        for (int j = 0; j < EPT; ++j) num[j] = h[j];
    }

    // ---- pass 2: denominator, coeffs sc[64..127] -> VGPR array ----
    float den[EPT];
    {
        float cd[64];
#pragma unroll
        for (int q = 0; q < 16; ++q) {
            float4 v = *reinterpret_cast<const float4*>(&sc[64 + 4 * q]);
            cd[4 * q] = v.x; cd[4 * q + 1] = v.y;
            cd[4 * q + 2] = v.z; cd[4 * q + 3] = v.w;
        }
        float h[EPT];
#pragma unroll
        for (int j = 0; j < EPT; ++j) h[j] = cd[63];
#pragma unroll
        for (int p = 62; p >= 0; --p)
#pragma unroll
            for (int j = 0; j < EPT; ++j)
                h[j] = fmaf(h[j], xs[j], cd[p]);
#pragma unroll
        for (int j = 0; j < EPT; ++j) den[j] = h[j];
    }

    float o[EPT];
#pragma unroll
    for (int j = 0; j < EPT; ++j) {
        float d = den[j] * xs[j];  // exponents 1..64
        o[j] = num[j] * __builtin_amdgcn_rcpf(fabsf(d) + 1.0f);
    }
    *reinterpret_cast<float4*>(out + idx)     = (float4){o[0], o[1], o[2], o[3]};
    *reinterpret_cast<float4*>(out + idx + 4) = (float4){o[4], o[5], o[6], o[7]};
}

extern "C" void kernel_launch(void* const* d_in, const int* in_sizes, int n_in,
                              void* d_out, int out_size, void* d_ws, size_t ws_size,
                              hipStream_t stream) {
    const float* x     = (const float*)d_in[0];
    const float* coeff = (const float*)d_in[1];
    float* out = (float*)d_out;
    int N = in_sizes[0];  // 4194304 = 2048 * 256 * 8 exactly

    int threads = 256;
    int elems_per_block = threads * EPT;
    int blocks = (N + elems_per_block - 1) / elems_per_block;  // 2048
    rationals_kernel<<<blocks, threads, 0, stream>>>(x, coeff, out, N);
}